// Round 8
// baseline (257.642 us; speedup 1.0000x reference)
//
#include <hip/hip_runtime.h>
#include <float.h>

// VQ-VAE vector quantizer, MI355X fp32 vector-ALU version, round 8.
// z: [32,64,32,32] f32, codebook: [1024,64] f32
// out (f32 flat): z_q [2097152] | loss [1] | indices-as-float [32768]
//
// Numerics contract (DO NOT CHANGE — bitwise-matches the numpy fp32 ref):
//  - code/pixel norms: numpy pairwise-sum tree over 64 rounded squares,
//    fp contract OFF
//  - dot: single c-ordered fma chain per (pixel, code)
//  - score: fl(fl(zz+ee) - 2*dot); strict-< first-min; codes ascending at
//    every reduction level (J, k-step, wave, slab)
//
// Round-8 change: round 7 was LDS-pipe-bound (1 LDS b128 per 6.4 FMA; the
// "broadcast" e-read costs like a distributed read). Register tile is now
// 4 px x 16 codes per lane-step (4 z-reads + 16 e-reads per 256 FMA =
// 1:12.8), 32 named accumulators. Block = 512 thr / 8 waves sharing a
// 256-px z-tile; each wave owns 16 codes of the block's 128-code slab.

#define DIM       64
#define N_EMB     1024
#define N_PX      32768
#define LOSS_OFF  2097152
#define IDX_OFF   2097153
// loss = 1.25 * sum / 2^21  (exact fp32 constant)
#define LOSS_SCALE 5.9604644775390625e-07f

#define PXT   256   // px per block
#define SLAB  128   // codes per block
#define ZSTR  256   // ldsZ px stride (float4 units)

// numpy pairwise_sum of squares over a 64-float global row, exact tree.
__device__ __forceinline__ float np_sumsq64_row(const float* __restrict__ row) {
    #pragma clang fp contract(off)
    float r[8];
    #pragma unroll
    for (int j = 0; j < 8; ++j) {
        float s = row[j] * row[j];
        #pragma unroll
        for (int m = 1; m < 8; ++m) {
            float p = row[j + 8 * m] * row[j + 8 * m];
            s = s + p;
        }
        r[j] = s;
    }
    return ((r[0] + r[1]) + (r[2] + r[3])) + ((r[4] + r[5]) + (r[6] + r[7]));
}

// Same tree from the LDS z tile ([c4][px], px stride ZSTR). Bit-identical.
__device__ __forceinline__ float np_sumsq64_lds(const float4* ldsZ, int px) {
    #pragma clang fp contract(off)
    float4 qa = ldsZ[px];              // c = 0..3   (j = 0..3)
    float4 qb = ldsZ[ZSTR + px];       // c = 4..7   (j = 4..7)
    float r0 = qa.x * qa.x, r1 = qa.y * qa.y, r2 = qa.z * qa.z, r3 = qa.w * qa.w;
    float r4 = qb.x * qb.x, r5 = qb.y * qb.y, r6 = qb.z * qb.z, r7 = qb.w * qb.w;
    #pragma unroll
    for (int m = 1; m < 8; ++m) {      // r[j] += sq[j + 8m], m ascending
        qa = ldsZ[(2 * m) * ZSTR + px];
        qb = ldsZ[(2 * m + 1) * ZSTR + px];
        float p;
        p = qa.x * qa.x; r0 = r0 + p;
        p = qa.y * qa.y; r1 = r1 + p;
        p = qa.z * qa.z; r2 = r2 + p;
        p = qa.w * qa.w; r3 = r3 + p;
        p = qb.x * qb.x; r4 = r4 + p;
        p = qb.y * qb.y; r5 = r5 + p;
        p = qb.z * qb.z; r6 = r6 + p;
        p = qb.w * qb.w; r7 = r7 + p;
    }
    return ((r0 + r1) + (r2 + r3)) + ((r4 + r5) + (r6 + r7));
}

// Phase 1: grid 1024 = 128 px-groups x 8 code-slabs; 512 thr (8 waves).
// Block: 256-px z-tile, 128-code slab. Lane owns 4 px (lane+64i); wave w
// owns codes [slab*128 + w*16, +16).
__global__ __launch_bounds__(512, 2)
void vq_argmin(const float* __restrict__ z, const float* __restrict__ cb,
               float* __restrict__ ws_val, int* __restrict__ ws_idx,
               float* __restrict__ out) {
    __shared__ float4 ldsZ[16 * PXT];    // [c4][px], 64 KB
    __shared__ float4 ldsE[SLAB * 16];   // [code][c4], 32 KB (bit-exact copy)
    __shared__ float  esq[SLAB];
    __shared__ float  cand_val[8 * PXT]; // 8 KB
    __shared__ int    cand_idx[8 * PXT]; // 8 KB

    const int tid  = threadIdx.x;
    const int lane = tid & 63;
    const int wave = __builtin_amdgcn_readfirstlane(tid >> 6);  // uniform
    const int g    = blockIdx.x >> 3;      // px-group 0..127 (256 px each)
    const int s    = blockIdx.x & 7;       // code slab 0..7 (128 codes)
    const int n0   = g * PXT;
    const int b    = n0 >> 10;
    const int hw0  = n0 & 1023;
    const size_t zbase = (size_t)b * 65536 + (size_t)hw0;   // z[b][c][hw]
    const int kb0  = s * SLAB;             // slab's first global code

    // ---- stage z tile -> LDS [c4][px] (transposing gather, coalesced) ----
    {
        const int px = tid & 255;
        const int ch = tid >> 8;           // 0..1
        #pragma unroll
        for (int r = 0; r < 8; ++r) {
            const int c4 = ch * 8 + r;
            const float* zp = z + zbase + (size_t)(c4 * 4) * 1024 + px;
            float4 v;
            v.x = zp[0];
            v.y = zp[1024];
            v.z = zp[2048];
            v.w = zp[3072];
            ldsZ[c4 * ZSTR + px] = v;
        }
    }
    // ---- stage codebook slab -> LDS (bit-exact float4 copy) ----
    {
        const float4* cb4 = (const float4*)cb;
        #pragma unroll
        for (int r = 0; r < 4; ++r)
            ldsE[r * 512 + tid] = cb4[kb0 * 16 + r * 512 + tid];
    }
    // ---- slab code norms (from global rows; same bits), numpy tree ----
    if (tid < SLAB)
        esq[tid] = np_sumsq64_row(cb + (size_t)(kb0 + tid) * DIM);

    __syncthreads();

    // ---- zz for this lane's four pixels (bit-identical tree) ----
    const float zz0 = np_sumsq64_lds(ldsZ, lane);
    const float zz1 = np_sumsq64_lds(ldsZ, lane + 64);
    const float zz2 = np_sumsq64_lds(ldsZ, lane + 128);
    const float zz3 = np_sumsq64_lds(ldsZ, lane + 192);

    // ---- argmin: wave's 16 codes in 2 k-steps of 8; 4 px x 8 codes tile ----
    float best0 = FLT_MAX, best1 = FLT_MAX, best2 = FLT_MAX, best3 = FLT_MAX;
    int   bidx0 = 0,       bidx1 = 0,       bidx2 = 0,       bidx3 = 0;
    const int lw = wave * 16;              // wave's local code base in slab
    for (int step = 0; step < 2; ++step) {
        const int lc = lw + step * 8;      // local code base of this k-step
        float d0_0 = 0.f, d0_1 = 0.f, d0_2 = 0.f, d0_3 = 0.f;
        float d0_4 = 0.f, d0_5 = 0.f, d0_6 = 0.f, d0_7 = 0.f;
        float d1_0 = 0.f, d1_1 = 0.f, d1_2 = 0.f, d1_3 = 0.f;
        float d1_4 = 0.f, d1_5 = 0.f, d1_6 = 0.f, d1_7 = 0.f;
        float d2_0 = 0.f, d2_1 = 0.f, d2_2 = 0.f, d2_3 = 0.f;
        float d2_4 = 0.f, d2_5 = 0.f, d2_6 = 0.f, d2_7 = 0.f;
        float d3_0 = 0.f, d3_1 = 0.f, d3_2 = 0.f, d3_3 = 0.f;
        float d3_4 = 0.f, d3_5 = 0.f, d3_6 = 0.f, d3_7 = 0.f;
        #pragma unroll
        for (int c4 = 0; c4 < 16; ++c4) {
            const float4 za = ldsZ[c4 * ZSTR + lane];        // px0
            const float4 zb = ldsZ[c4 * ZSTR + 64 + lane];   // px1
            const float4 zc = ldsZ[c4 * ZSTR + 128 + lane];  // px2
            const float4 zd = ldsZ[c4 * ZSTR + 192 + lane];  // px3
#define VQ_CODE(J) \
            { \
                const float4 e4 = ldsE[(lc + (J)) * 16 + c4]; \
                d0_##J = __builtin_fmaf(e4.x, za.x, d0_##J); \
                d0_##J = __builtin_fmaf(e4.y, za.y, d0_##J); \
                d0_##J = __builtin_fmaf(e4.z, za.z, d0_##J); \
                d0_##J = __builtin_fmaf(e4.w, za.w, d0_##J); \
                d1_##J = __builtin_fmaf(e4.x, zb.x, d1_##J); \
                d1_##J = __builtin_fmaf(e4.y, zb.y, d1_##J); \
                d1_##J = __builtin_fmaf(e4.z, zb.z, d1_##J); \
                d1_##J = __builtin_fmaf(e4.w, zb.w, d1_##J); \
                d2_##J = __builtin_fmaf(e4.x, zc.x, d2_##J); \
                d2_##J = __builtin_fmaf(e4.y, zc.y, d2_##J); \
                d2_##J = __builtin_fmaf(e4.z, zc.z, d2_##J); \
                d2_##J = __builtin_fmaf(e4.w, zc.w, d2_##J); \
                d3_##J = __builtin_fmaf(e4.x, zd.x, d3_##J); \
                d3_##J = __builtin_fmaf(e4.y, zd.y, d3_##J); \
                d3_##J = __builtin_fmaf(e4.z, zd.z, d3_##J); \
                d3_##J = __builtin_fmaf(e4.w, zd.w, d3_##J); \
            }
            VQ_CODE(0) VQ_CODE(1) VQ_CODE(2) VQ_CODE(3)
            VQ_CODE(4) VQ_CODE(5) VQ_CODE(6) VQ_CODE(7)
#undef VQ_CODE
        }
        // scores: J ascending => first-min kept (global code = kb0+lc+J)
#define VQ_SCORE(J) \
        { \
            const float ee = esq[lc + (J)]; \
            const int   ki = kb0 + lc + (J); \
            float sc0, sc1, sc2, sc3; \
            { \
                _Pragma("clang fp contract(off)") \
                const float p0 = zz0 + ee; \
                const float p1 = zz1 + ee; \
                const float p2 = zz2 + ee; \
                const float p3 = zz3 + ee; \
                sc0 = p0 - 2.0f * d0_##J; \
                sc1 = p1 - 2.0f * d1_##J; \
                sc2 = p2 - 2.0f * d2_##J; \
                sc3 = p3 - 2.0f * d3_##J; \
            } \
            if (sc0 < best0) { best0 = sc0; bidx0 = ki; } \
            if (sc1 < best1) { best1 = sc1; bidx1 = ki; } \
            if (sc2 < best2) { best2 = sc2; bidx2 = ki; } \
            if (sc3 < best3) { best3 = sc3; bidx3 = ki; } \
        }
        VQ_SCORE(0) VQ_SCORE(1) VQ_SCORE(2) VQ_SCORE(3)
        VQ_SCORE(4) VQ_SCORE(5) VQ_SCORE(6) VQ_SCORE(7)
#undef VQ_SCORE
    }
    cand_val[wave * PXT + lane]       = best0;
    cand_idx[wave * PXT + lane]       = bidx0;
    cand_val[wave * PXT + 64 + lane]  = best1;
    cand_idx[wave * PXT + 64 + lane]  = bidx1;
    cand_val[wave * PXT + 128 + lane] = best2;
    cand_idx[wave * PXT + 128 + lane] = bidx2;
    cand_val[wave * PXT + 192 + lane] = best3;
    cand_idx[wave * PXT + 192 + lane] = bidx3;
    __syncthreads();

    // ---- block reduce (8 waves, ascending w == ascending k) -> ws ----
    if (tid < PXT) {
        float bv = cand_val[tid];
        int   bi = cand_idx[tid];
        #pragma unroll
        for (int w = 1; w < 8; ++w) {
            float v = cand_val[w * PXT + tid];
            int   i = cand_idx[w * PXT + tid];
            if (v < bv || (v == bv && i < bi)) { bv = v; bi = i; }
        }
        ws_val[s * N_PX + n0 + tid] = bv;
        ws_idx[s * N_PX + n0 + tid] = bi;
    }
    // zero the loss accumulator for phase 2 (stream-ordered before vq_out)
    if (blockIdx.x == 0 && tid == 0) out[LOSS_OFF] = 0.f;
}

// Phase 2: grid 512 x 256 thr; block = 64 px. Reduce 8 slab-candidates
// (ascending slab == ascending k), write indices, z_q, loss.
__global__ __launch_bounds__(256, 4)
void vq_out(const float* __restrict__ z, const float* __restrict__ cb,
            const float* __restrict__ ws_val, const int* __restrict__ ws_idx,
            float* __restrict__ out) {
    __shared__ int   fidx[64];
    __shared__ float lred[4];

    const int tid  = threadIdx.x;
    const int lane = tid & 63;
    const int wave = tid >> 6;
    const int n0   = blockIdx.x * 64;
    const int b    = n0 >> 10;
    const int hw0  = n0 & 1023;
    const size_t zbase = (size_t)b * 65536 + (size_t)hw0;

    if (tid < 64) {
        float bv = ws_val[n0 + tid];
        int   bi = ws_idx[n0 + tid];
        #pragma unroll
        for (int sl = 1; sl < 8; ++sl) {
            float v = ws_val[sl * N_PX + n0 + tid];
            int   i = ws_idx[sl * N_PX + n0 + tid];
            if (v < bv || (v == bv && i < bi)) { bv = v; bi = i; }
        }
        fidx[tid] = bi;
        out[IDX_OFF + n0 + tid] = (float)bi;
    }
    __syncthreads();

    const int px = tid & 63;
    const int cg = tid >> 6;      // 0..3 -> channels cg*16 .. cg*16+15
    const int mi = fidx[px];
    float lacc = 0.f;
    #pragma unroll
    for (int i = 0; i < 16; ++i) {
        const int c = cg * 16 + i;
        float q  = cb[mi * DIM + c];                    // L2-resident gather
        size_t go = zbase + (size_t)c * 1024 + px;
        float zv = z[go];                               // coalesced
        float d  = q - zv;
        lacc = __builtin_fmaf(d, d, lacc);
        out[go] = q;                                    // coalesced
    }
    #pragma unroll
    for (int off = 32; off > 0; off >>= 1)
        lacc += __shfl_down(lacc, off, 64);
    if (lane == 0) lred[wave] = lacc;
    __syncthreads();
    if (tid == 0) {
        float t = (lred[0] + lred[1]) + (lred[2] + lred[3]);
        atomicAdd(&out[LOSS_OFF], t * LOSS_SCALE);
    }
}

extern "C" void kernel_launch(void* const* d_in, const int* in_sizes, int n_in,
                              void* d_out, int out_size, void* d_ws, size_t ws_size,
                              hipStream_t stream) {
    const float* z  = (const float*)d_in[0];   // 2097152 f32
    const float* cb = (const float*)d_in[1];   // 65536 f32
    float* out = (float*)d_out;
    // workspace: 8 x 32768 vals (1 MB) + 8 x 32768 idx (1 MB)
    float* ws_val = (float*)d_ws;
    int*   ws_idx = (int*)((char*)d_ws + 8u * N_PX * sizeof(float));

    vq_argmin<<<1024, 512, 0, stream>>>(z, cb, ws_val, ws_idx, out);
    vq_out<<<512, 256, 0, stream>>>(z, cb, ws_val, ws_idx, out);
}